// Round 1
// baseline (182.174 us; speedup 1.0000x reference)
//
#include <hip/hip_runtime.h>
#include <math.h>

// LSTM_55344948576591 — fully fused single-kernel implementation.
// B=256, T=32, CNN_DIM=512, HW=14 (196 elems/channel), HID=8, V=37, G=4*HID=32.
// One block per batch (grid=256, block=512). Per-batch pipeline:
//   A) adaptive avg-pool over 196 elems/channel (dominant HBM read: 102.8 MB total)
//   B) x0 = pooled @ W_in.T + b_in
//   C) xg[t][j] = xs[t] @ W_ih.T + b_ih + b_hh  (teacher-forcing inputs, parallel over t)
//   D) sequential LSTM recurrence in wave 0 (shfl-held h/c state)
//   E) logits  F) softmax over TIME axis (dim=1)

#define BDIM 512

__device__ __forceinline__ float wave_reduce_sum(float v) {
#pragma unroll
    for (int off = 32; off; off >>= 1) v += __shfl_down(v, off, 64);
    return v;
}

__device__ __forceinline__ float sigf(float x) { return 1.0f / (1.0f + __expf(-x)); }
// tanh via exp; saturates correctly at +/-1 for large |x|
__device__ __forceinline__ float tanhfast(float x) { return 1.0f - 2.0f / (__expf(2.0f * x) + 1.0f); }

__global__ __launch_bounds__(BDIM) void lstm_fused(
    const float* __restrict__ features, const float* __restrict__ captions,
    const float* __restrict__ W_ih, const float* __restrict__ b_ih,
    const float* __restrict__ W_hh, const float* __restrict__ b_hh,
    const float* __restrict__ W_in, const float* __restrict__ b_in,
    const float* __restrict__ W_out, const float* __restrict__ b_out,
    const int* __restrict__ isTraining, float* __restrict__ out)
{
    constexpr int T = 32, V = 37, HID = 8, C = 512, NPIX = 196, G = 32;

    __shared__ float pooled[C];        // channel means
    __shared__ float xs[T * V];        // LSTM inputs per step (x0, then captions[0..T-2])
    __shared__ float wih[G * V];       // W_ih staged
    __shared__ float xg[T * G];        // precomputed input-gate contributions (+both biases)
    __shared__ float hist[T * HID];    // h history (training path)
    __shared__ float lg[T * V];        // logits -> exp values
    __shared__ float bsum[G];          // b_ih + b_hh
    __shared__ float inv_s[V];         // softmax 1/denominator per vocab column

    const int b    = blockIdx.x;
    const int tid  = threadIdx.x;
    const int lane = tid & 63;
    const int w    = tid >> 6;   // wave id, 0..7

    // ---------------- Phase A: pooling (the HBM-bound part) ----------------
    // wave w handles channels c = w + 8*j, j=0..63; 8 channels in flight per iter.
    const float* featB = features + (size_t)b * C * NPIX;
    const int li = (lane < 49) ? lane : 0;   // always-load (no divergent branch around loads)
    for (int grp = 0; grp < 8; ++grp) {
        float s[8];
#pragma unroll
        for (int u = 0; u < 8; ++u) {
            const int c = w + 8 * (grp * 8 + u);
            // 196 floats = 49 float4, base 784-byte (16B) aligned
            const float4 v = ((const float4*)(featB + c * NPIX))[li];
            const float s4 = (v.x + v.y) + (v.z + v.w);
            s[u] = (lane < 49) ? s4 : 0.0f;
        }
#pragma unroll
        for (int u = 0; u < 8; ++u) {
            const float tot = wave_reduce_sum(s[u]);
            if (lane == 0) pooled[w + 8 * (grp * 8 + u)] = tot * (1.0f / 196.0f);
        }
    }

    // Stage small tensors into LDS (independent of phase A; before the barrier).
    for (int i = tid; i < G * V; i += BDIM) wih[i] = W_ih[i];
    for (int i = tid + V; i < T * V; i += BDIM) xs[i] = captions[(size_t)b * T * V + (i - V)];
    if (tid < G) bsum[tid] = b_ih[tid] + b_hh[tid];
    __syncthreads();

    // ---------------- Phase B: x0 = pooled @ W_in.T + b_in ----------------
    for (int v = w; v < V; v += 8) {
        const float* wr = W_in + (size_t)v * C;
        float p = 0.0f;
#pragma unroll
        for (int k = 0; k < 8; ++k) p += pooled[lane + 64 * k] * wr[lane + 64 * k];
        p = wave_reduce_sum(p);
        if (lane == 0) xs[v] = p + b_in[v];
    }
    __syncthreads();

    // ---------------- Phase C: xg[t][j] = xs[t]@W_ih.T + (b_ih+b_hh) ----------------
    for (int e = tid; e < T * G; e += BDIM) {
        const int t = e >> 5, j = e & 31;
        const float* xr = xs + t * V;
        const float* wr = wih + j * V;
        float acc = bsum[j];
#pragma unroll
        for (int v = 0; v < V; ++v) acc += xr[v] * wr[v];
        xg[e] = acc;
    }
    __syncthreads();

    // ---------------- Phase D: sequential recurrence (wave 0 only) ----------------
    const bool train = (isTraining[0] != 0);
    if (w == 0) {
        const int j = lane & 31;     // gate index (lanes 32-63 duplicate, harmless)
        const int k8 = lane & 7;
        float whh_r[HID];
#pragma unroll
        for (int k = 0; k < HID; ++k) whh_r[k] = W_hh[j * HID + k];
        float wout_r[HID];
        float bout_r = 0.0f;
        if (lane < V) {
#pragma unroll
            for (int k = 0; k < HID; ++k) wout_r[k] = W_out[lane * HID + k];
            bout_r = b_out[lane];
        }
        float h = 0.0f, c = 0.0f;    // valid on lanes 0..7
        float prevout = 0.0f;        // greedy path: previous pre-softmax logits (lanes < V)

        for (int t = 0; t < T; ++t) {
            float gate;
            if (train || t == 0) {
                gate = xg[t * G + j];
            } else {
                float acc = bsum[j];
                const float* wr = wih + j * V;
#pragma unroll
                for (int v = 0; v < V; ++v) acc += __shfl(prevout, v, 64) * wr[v];
                gate = acc;
            }
#pragma unroll
            for (int k = 0; k < HID; ++k) gate += __shfl(h, k, 64) * whh_r[k];

            const int sec = lane >> 3;              // 0:i 1:f 2:g 3:o
            const float a = (sec == 2) ? tanhfast(gate) : sigf(gate);

            const float ig = __shfl(a, k8, 64);
            const float fg = __shfl(a, 8 + k8, 64);
            const float gg = __shfl(a, 16 + k8, 64);
            const float og = __shfl(a, 24 + k8, 64);
            c = fg * c + ig * gg;                    // meaningful on lanes 0..7
            h = og * tanhfast(c);

            if (train) {
                if (lane < HID) hist[t * HID + lane] = h;
            } else {
                float o = bout_r;
#pragma unroll
                for (int k = 0; k < HID; ++k) o += __shfl(h, k, 64) * wout_r[k];
                if (lane < V) lg[t * V + lane] = o;
                prevout = o;
            }
        }
    }
    __syncthreads();

    // ---------------- Phase E: logits (training path) ----------------
    if (train) {
        for (int e = tid; e < T * V; e += BDIM) {
            const int t = e / V, v = e - t * V;
            const float* hr = hist + t * HID;
            const float* wr = W_out + v * HID;
            float acc = b_out[v];
#pragma unroll
            for (int k = 0; k < HID; ++k) acc += hr[k] * wr[k];
            lg[e] = acc;
        }
    }
    __syncthreads();

    // ---------------- Phase F: softmax over TIME axis (dim=1) ----------------
    if (tid < V) {
        float m = -1e30f;
#pragma unroll
        for (int t = 0; t < T; ++t) m = fmaxf(m, lg[t * V + tid]);
        float s = 0.0f;
#pragma unroll
        for (int t = 0; t < T; ++t) {
            const float e = __expf(lg[t * V + tid] - m);
            lg[t * V + tid] = e;
            s += e;
        }
        inv_s[tid] = 1.0f / s;
    }
    __syncthreads();

    float* outB = out + (size_t)b * T * V;
    for (int e = tid; e < T * V; e += BDIM) {
        const int t = e / V, v = e - t * V;
        outB[e] = lg[e] * inv_s[v];
    }
}

extern "C" void kernel_launch(void* const* d_in, const int* in_sizes, int n_in,
                              void* d_out, int out_size, void* d_ws, size_t ws_size,
                              hipStream_t stream) {
    const float* features = (const float*)d_in[0];
    const float* captions = (const float*)d_in[1];
    const float* W_ih     = (const float*)d_in[2];
    const float* b_ih     = (const float*)d_in[3];
    const float* W_hh     = (const float*)d_in[4];
    const float* b_hh     = (const float*)d_in[5];
    const float* W_in     = (const float*)d_in[6];
    const float* b_in     = (const float*)d_in[7];
    const float* W_out    = (const float*)d_in[8];
    const float* b_out    = (const float*)d_in[9];
    const int*   isTrain  = (const int*)d_in[10];
    float* out = (float*)d_out;

    lstm_fused<<<256, BDIM, 0, stream>>>(features, captions, W_ih, b_ih, W_hh, b_hh,
                                         W_in, b_in, W_out, b_out, isTrain, out);
}